// Round 16
// baseline (2552.804 us; speedup 1.0000x reference)
//
#include <hip/hip_runtime.h>

// Discriminator: emb+MLP (GEMMs) -> bidirectional LSTM (wh-resident persistent blocks) -> proj
// B=256 T=512 HD=256 FEAT=48 G=1024
// R14 = R13 (fused LSTM+next-chunk-GEMM) with the LSTM step re-ordered:
//   - acc starts at 0; gx is added in the GATE phase (R2 pattern) -> the 8 gx loads issue
//     at the barrier and their remote-L2/HBM latency hides under the whole MFMA phase.
//   - streamed nt7 ring 2-deep (sA[3], prefetch kt+2) -> L2 latency (~200cy) covered.

#define DI __device__ __forceinline__
typedef unsigned short u16;
typedef __attribute__((ext_vector_type(8))) __bf16 bf16x8;
typedef __attribute__((ext_vector_type(8))) short short8;
typedef __attribute__((ext_vector_type(4))) float f32x4;
typedef __attribute__((ext_vector_type(2))) unsigned int u32x2;

DI float bf2f(u16 u){ unsigned v = ((unsigned)u)<<16; float f; __builtin_memcpy(&f,&v,4); return f; }
DI u16 f2bf(float f){ unsigned u; __builtin_memcpy(&u,&f,4);
  unsigned r = (u + 0x7fffu + ((u>>16)&1u))>>16; return (u16)r; }
DI float sigf(float x){ return __builtin_amdgcn_rcpf(1.f + __builtin_amdgcn_exp2f(-1.44269504f*x)); }
DI float tanh_(float x){ return 1.f - 2.f*__builtin_amdgcn_rcpf(1.f + __builtin_amdgcn_exp2f(2.88539008f*x)); }

// async global->LDS, 16B/lane; LDS dest = wave-uniform base + lane*16 (HW rule).
DI void gl_lds16(const void* g, void* lds){
  __builtin_amdgcn_global_load_lds(
    (const __attribute__((address_space(1))) unsigned int*)g,
    (__attribute__((address_space(3))) unsigned int*)lds,
    16, 0, 0);
}
DI bf16x8 ld8(const void* p){ return *(const bf16x8*)p; }

__global__ void disc_wsfail(float* out){ out[0] = 1.0e9f; }

// ---------------- prep: weight transforms (R2 layouts) ----------------
__global__ __launch_bounds__(256) void disc_prep(
    const float* __restrict__ embw, const float* __restrict__ w1, const float* __restrict__ w2,
    const float* __restrict__ wi_f, const float* __restrict__ wi_r,
    const float* __restrict__ wh_f, const float* __restrict__ wh_r,
    const float* __restrict__ bi_f, const float* __restrict__ bh_f,
    const float* __restrict__ bi_r, const float* __restrict__ bh_r,
    u16* __restrict__ w1effT, u16* __restrict__ w2bT, u16* __restrict__ wibT,
    u16* __restrict__ whp, float* __restrict__ biasf)
{
  int bx = blockIdx.x, tid = threadIdx.x;
  if (bx < 64) {                           // w1effT[n][f] 256x64, emb folded, f>=48 zero
    int i = bx*256 + tid; int n = i>>6, f = i&63;
    float v = 0.f;
    if (f < 8) v = w1[f*256 + n];
    else if (f < 48) {
      int ff = f-8, c = ff/10, cls = ff%10;
      #pragma unroll
      for (int e=0;e<8;e++) v += embw[(c*10+cls)*8 + e] * w1[(8 + c*8 + e)*256 + n];
    }
    w1effT[n*64 + f] = f2bf(v);
  } else if (bx < 320) {                   // w2bT[n][k] 256x256
    int i = (bx-64)*256 + tid; int n = i>>8, k = i&255;
    w2bT[i] = f2bf(w2[k*256 + n]);
  } else if (bx < 2368) {                  // wibT[n][k] 2048x256, n = dir*1024+g
    int i = (bx-320)*256 + tid; int n = i>>8, k = i&255;
    const float* wi = (n < 1024) ? wi_f : wi_r; int g = n & 1023;
    wibT[i] = f2bf(wi[k*1024 + g]);
  } else if (bx < 4416) {                  // whp[dir][w][kt][nt][lane][j] B-frag order
    int i = (bx-2368)*256 + tid;
    int j = i&7, lane = (i>>3)&63, nt = (i>>9)&7, kt = (i>>12)&7, w = (i>>15)&7, dir = (i>>18)&1;
    int k = kt*32 + (lane>>4)*8 + j;
    int g = (nt>>1)*256 + w*32 + (nt&1)*16 + (lane&15);
    const float* wh = dir ? wh_r : wh_f;
    whp[i] = f2bf(wh[k*1024 + g]);
  } else {                                 // biasf[dir*1024+g] = bi+bh
    int i = (bx-4416)*256 + tid;
    if (i < 2048) { int dir = i>>10, g = i&1023;
      biasf[i] = dir ? (bi_r[g]+bh_r[g]) : (bi_f[g]+bh_f[g]); }
  }
}

// ---------------- k1a: x2 = lrelu(x0 @ w1eff + b1), bf16 [b*512+t][256] ----------------
__global__ __launch_bounds__(256) void disc_k1a(const float* __restrict__ x0,
    const u16* __restrict__ w1effT, const float* __restrict__ b1, u16* __restrict__ x2)
{
  __shared__ __align__(16) u16 a_lds[64*64];
  __shared__ __align__(16) u16 b_lds[256*64];
  int tid=threadIdx.x, lane=tid&63, wv=tid>>6;
  int m0 = blockIdx.x*64;
  #pragma unroll
  for (int r2=0;r2<8;r2++){
    int c = r2*256 + tid;
    gl_lds16((const char*)w1effT + (size_t)c*16, (char*)b_lds + (r2*256 + wv*64)*16);
  }
  if (tid < 128){
    int row = tid>>1, half = tid&1;
    const float* src = x0 + (size_t)(m0+row)*48 + half*24;
    u16 tmp[24];
    #pragma unroll
    for (int i=0;i<24;i++) tmp[i] = f2bf(src[i]);
    #pragma unroll
    for (int i=0;i<3;i++) *(short8*)&a_lds[row*64 + half*24 + i*8] = *(short8*)&tmp[i*8];
    if (half){ short8 z = (short8){0,0,0,0,0,0,0,0};
      *(short8*)&a_lds[row*64 + 48] = z; *(short8*)&a_lds[row*64 + 56] = z; }
  }
  asm volatile("s_waitcnt vmcnt(0)" ::: "memory");
  __syncthreads();
  bf16x8 Af0 = ld8(&a_lds[(wv*16 + (lane&15))*64 + (lane>>4)*8]);
  bf16x8 Af1 = ld8(&a_lds[(wv*16 + (lane&15))*64 + 32 + (lane>>4)*8]);
  f32x4 acc[16];
  #pragma unroll
  for (int ni=0;ni<16;ni++){
    acc[ni] = (f32x4){0.f,0.f,0.f,0.f};
    bf16x8 B0 = ld8(&b_lds[(ni*16 + (lane&15))*64 + (lane>>4)*8]);
    bf16x8 B1 = ld8(&b_lds[(ni*16 + (lane&15))*64 + 32 + (lane>>4)*8]);
    acc[ni] = __builtin_amdgcn_mfma_f32_16x16x32_bf16(Af0, B0, acc[ni], 0,0,0);
    acc[ni] = __builtin_amdgcn_mfma_f32_16x16x32_bf16(Af1, B1, acc[ni], 0,0,0);
  }
  #pragma unroll
  for (int ni=0;ni<16;ni++){
    float bb = b1[ni*16 + (lane&15)];
    #pragma unroll
    for (int r=0;r<4;r++){
      float v = acc[ni][r] + bb; v = v>=0.f ? v : 0.1f*v;
      int row = m0 + wv*16 + (lane>>4)*4 + r;
      x2[(size_t)row*256 + ni*16 + (lane&15)] = f2bf(v);
    }
  }
}

// ---------------- k1b: x3t = lrelu(x2 @ w2 + b2), permuted [t][b][256] ----------------
__global__ __launch_bounds__(256) void disc_k1b(const u16* __restrict__ x2,
    const u16* __restrict__ w2bT, const float* __restrict__ b2, u16* __restrict__ x3t)
{
  __shared__ __align__(16) u16 a_lds[64*64];
  __shared__ __align__(16) u16 b_lds[256*64];
  int tid=threadIdx.x, lane=tid&63, wv=tid>>6;
  int m0 = blockIdx.x*64;
  f32x4 acc[16];
  #pragma unroll
  for (int ni=0;ni<16;ni++) acc[ni] = (f32x4){0.f,0.f,0.f,0.f};
  for (int kt=0;kt<4;kt++){
    #pragma unroll
    for (int r2=0;r2<2;r2++){
      int c = r2*256 + tid, row = c>>3, cb = (c&7)*16;
      gl_lds16((const char*)x2 + (size_t)(m0+row)*512 + kt*128 + cb,
               (char*)a_lds + (r2*256 + wv*64)*16);
    }
    #pragma unroll
    for (int r2=0;r2<8;r2++){
      int c = r2*256 + tid, row = c>>3, cb = (c&7)*16;
      gl_lds16((const char*)w2bT + (size_t)row*512 + kt*128 + cb,
               (char*)b_lds + (r2*256 + wv*64)*16);
    }
    asm volatile("s_waitcnt vmcnt(0)" ::: "memory");
    __syncthreads();
    bf16x8 Af0 = ld8(&a_lds[(wv*16 + (lane&15))*64 + (lane>>4)*8]);
    bf16x8 Af1 = ld8(&a_lds[(wv*16 + (lane&15))*64 + 32 + (lane>>4)*8]);
    #pragma unroll
    for (int ni=0;ni<16;ni++){
      bf16x8 B0 = ld8(&b_lds[(ni*16 + (lane&15))*64 + (lane>>4)*8]);
      bf16x8 B1 = ld8(&b_lds[(ni*16 + (lane&15))*64 + 32 + (lane>>4)*8]);
      acc[ni] = __builtin_amdgcn_mfma_f32_16x16x32_bf16(Af0, B0, acc[ni], 0,0,0);
      acc[ni] = __builtin_amdgcn_mfma_f32_16x16x32_bf16(Af1, B1, acc[ni], 0,0,0);
    }
    __syncthreads();
  }
  #pragma unroll
  for (int ni=0;ni<16;ni++){
    float bb = b2[ni*16 + (lane&15)];
    #pragma unroll
    for (int r=0;r<4;r++){
      float v = acc[ni][r] + bb; v = v>=0.f ? v : 0.1f*v;
      int rowg = m0 + wv*16 + (lane>>4)*4 + r;     // = b*512 + t
      int b = rowg>>9, t = rowg&511;
      x3t[((size_t)t*256 + b)*256 + ni*16 + (lane&15)] = f2bf(v);
    }
  }
}

// ---------------- k1c (standalone, 32-step chunk): gxc = bf16(x3 @ wi + bias) ----------
// gxc u16 idx = ((((tloc*2+dir)*16+blk)*8+w)*8+nt)*256 + lane*4 + r, tloc in [0,32)
__global__ __launch_bounds__(256) void disc_k1c(const u16* __restrict__ x3t,
    const u16* __restrict__ wibT, const float* __restrict__ biasf,
    u16* __restrict__ gxc, int chunk)
{
  __shared__ __align__(16) u16 a_lds[128*64];
  __shared__ __align__(16) u16 b_lds[128*64];
  int tid=threadIdx.x, lane=tid&63, wv=tid>>6;
  int id = (blockIdx.x & 7)*128 + (blockIdx.x >> 3);   // XCD swizzle, 1024 blocks
  int dirn = id >> 9;
  int rem  = id & 511;
  int tloc = rem >> 4;           // 0..31
  int msub = (rem >> 3) & 1;
  int nt8  = rem & 7;
  int tp    = chunk*32 + tloc;
  int tglob = dirn ? (511 - tp) : tp;
  int m0 = tglob*256 + msub*128;
  int n0 = dirn*1024 + nt8*128;
  int wm = wv>>1, wn = wv&1;
  f32x4 acc[4][4];
  #pragma unroll
  for (int mi=0;mi<4;mi++)
    #pragma unroll
    for (int ni=0;ni<4;ni++) acc[mi][ni] = (f32x4){0.f,0.f,0.f,0.f};
  for (int kt=0;kt<4;kt++){
    #pragma unroll
    for (int r2=0;r2<4;r2++){
      int c = r2*256 + tid, row = c>>3, cb = (c&7)*16;
      gl_lds16((const char*)x3t + (size_t)(m0+row)*512 + kt*128 + cb,
               (char*)a_lds + (r2*256 + wv*64)*16);
    }
    #pragma unroll
    for (int r2=0;r2<4;r2++){
      int c = r2*256 + tid, row = c>>3, cb = (c&7)*16;
      gl_lds16((const char*)wibT + (size_t)(n0+row)*512 + kt*128 + cb,
               (char*)b_lds + (r2*256 + wv*64)*16);
    }
    asm volatile("s_waitcnt vmcnt(0)" ::: "memory");
    __syncthreads();
    bf16x8 Af[4][2], Bf[4][2];
    #pragma unroll
    for (int mi=0;mi<4;mi++){
      Af[mi][0] = ld8(&a_lds[(wm*64+mi*16+(lane&15))*64 + (lane>>4)*8]);
      Af[mi][1] = ld8(&a_lds[(wm*64+mi*16+(lane&15))*64 + 32 + (lane>>4)*8]);
    }
    #pragma unroll
    for (int ni=0;ni<4;ni++){
      Bf[ni][0] = ld8(&b_lds[(wn*64+ni*16+(lane&15))*64 + (lane>>4)*8]);
      Bf[ni][1] = ld8(&b_lds[(wn*64+ni*16+(lane&15))*64 + 32 + (lane>>4)*8]);
    }
    #pragma unroll
    for (int ks=0;ks<2;ks++)
      #pragma unroll
      for (int mi=0;mi<4;mi++)
        #pragma unroll
        for (int ni=0;ni<4;ni++)
          acc[mi][ni] = __builtin_amdgcn_mfma_f32_16x16x32_bf16(Af[mi][ks], Bf[ni][ks], acc[mi][ni], 0,0,0);
    __syncthreads();
  }
  float bb[4];
  #pragma unroll
  for (int ni=0;ni<4;ni++) bb[ni] = biasf[n0 + wn*64 + ni*16 + (lane&15)];
  #pragma unroll
  for (int mi=0;mi<4;mi++){
    int bbase = msub*128 + wm*64 + mi*16;
    #pragma unroll
    for (int ni=0;ni<4;ni++){
      int g0 = (n0 + wn*64 + ni*16) & 1023;
      int gt = g0>>8, h0 = g0&255;
      int w8 = h0>>5, p = (h0>>4)&1, nt = gt*2 + p;
      size_t fb = (((((size_t)tloc*2 + dirn)*16 + (bbase>>4))*8 + w8)*8 + nt)*256;
      u32x2 v;
      v.x = (unsigned)f2bf(acc[mi][ni][0]+bb[ni]) | ((unsigned)f2bf(acc[mi][ni][1]+bb[ni])<<16);
      v.y = (unsigned)f2bf(acc[mi][ni][2]+bb[ni]) | ((unsigned)f2bf(acc[mi][ni][3]+bb[ni])<<16);
      *(u32x2*)((char*)gxc + (fb + (size_t)lane*4)*2) = v;
    }
  }
}

// ---------------- fused: blocks 0-31 = LSTM chunk c (reads gxr); blocks 32-1055 = ------
// GEMM chunk c+1 into gxw (8 waves, 4x2 frags/wave). 512 thr, uniform barriers.
__global__ __launch_bounds__(512) __attribute__((amdgpu_waves_per_eu(2, 2)))
void disc_fused(const u16* __restrict__ gxr, u16* __restrict__ gxw,
                const u16* __restrict__ whp,
                const u16* __restrict__ x3t, const u16* __restrict__ wibT,
                const float* __restrict__ biasf,
                u16* __restrict__ qsave, float* __restrict__ ssave,
                float* __restrict__ qout, int chunk)
{
  __shared__ __align__(16) u16 wh_lds[65536];   // LSTM: 128KB wh; GEMM: a_lds/b_lds reuse
  __shared__ __align__(16) u16 qbuf0[4096];
  __shared__ __align__(16) u16 qbuf1[4096];
  int tid=threadIdx.x, lane=tid&63, w=tid>>6;

  if (blockIdx.x >= 32){
    // ======== GEMM part: gx chunk+1 -> gxw ========
    u16* a_lds = wh_lds;          // 16 KB
    u16* b_lds = wh_lds + 8192;   // 16 KB
    int gid = (int)blockIdx.x - 32;
    int id = (gid & 7)*128 + (gid >> 3);   // XCD swizzle, 1024 blocks
    int dirn = id >> 9;
    int rem  = id & 511;
    int tloc = rem >> 4;          // 0..31
    int msub = (rem >> 3) & 1;
    int nt8  = rem & 7;
    int tp    = (chunk+1)*32 + tloc;
    int tglob = dirn ? (511 - tp) : tp;
    int m0 = tglob*256 + msub*128;
    int n0 = dirn*1024 + nt8*128;
    int wm = w>>2, wn = w&3;      // 2 x 4 wave grid; wave = 64 rows x 32 cols
    f32x4 acc[4][2];
    #pragma unroll
    for (int mi=0;mi<4;mi++)
      #pragma unroll
      for (int ni=0;ni<2;ni++) acc[mi][ni] = (f32x4){0.f,0.f,0.f,0.f};
    for (int kt=0;kt<4;kt++){
      #pragma unroll
      for (int r2=0;r2<2;r2++){
        int c = r2*512 + tid, row = c>>3, cb = (c&7)*16;
        gl_lds16((const char*)x3t + (size_t)(m0+row)*512 + kt*128 + cb,
                 (char*)a_lds + (r2*512 + w*64)*16);
        int c2 = r2*512 + tid, row2 = c2>>3, cb2 = (c2&7)*16;
        gl_lds16((const char*)wibT + (size_t)(n0+row2)*512 + kt*128 + cb2,
                 (char*)b_lds + (r2*512 + w*64)*16);
      }
      asm volatile("s_waitcnt vmcnt(0)" ::: "memory");
      __syncthreads();
      bf16x8 Af[4][2], Bf[2][2];
      #pragma unroll
      for (int mi=0;mi<4;mi++){
        Af[mi][0] = ld8(&a_lds[(wm*64+mi*16+(lane&15))*64 + (lane>>4)*8]);
        Af[mi][1] = ld8(&a_lds[(wm*64+mi*16+(lane&15))*64 + 32 + (lane>>4)*8]);
      }
      #pragma unroll
      for (int ni=0;ni<2;ni++){
        Bf[ni][0] = ld8(&b_lds[(wn*32+ni*16+(lane&15))*64 + (lane>>4)*8]);
        Bf[ni][1] = ld8(&b_lds[(wn*32+ni*16+(lane&15))*64 + 32 + (lane>>4)*8]);
      }
      #pragma unroll
      for (int ks=0;ks<2;ks++)
        #pragma unroll
        for (int mi=0;mi<4;mi++)
          #pragma unroll
          for (int ni=0;ni<2;ni++)
            acc[mi][ni] = __builtin_amdgcn_mfma_f32_16x16x32_bf16(Af[mi][ks], Bf[ni][ks], acc[mi][ni], 0,0,0);
      __syncthreads();
    }
    float bb[2];
    #pragma unroll
    for (int ni=0;ni<2;ni++) bb[ni] = biasf[n0 + wn*32 + ni*16 + (lane&15)];
    #pragma unroll
    for (int mi=0;mi<4;mi++){
      int bbase = msub*128 + wm*64 + mi*16;
      #pragma unroll
      for (int ni=0;ni<2;ni++){
        int g0 = (n0 + wn*32 + ni*16) & 1023;
        int gt = g0>>8, h0 = g0&255;
        int w8 = h0>>5, p = (h0>>4)&1, nt = gt*2 + p;
        size_t fb = (((((size_t)tloc*2 + dirn)*16 + (bbase>>4))*8 + w8)*8 + nt)*256;
        u32x2 v;
        v.x = (unsigned)f2bf(acc[mi][ni][0]+bb[ni]) | ((unsigned)f2bf(acc[mi][ni][1]+bb[ni])<<16);
        v.y = (unsigned)f2bf(acc[mi][ni][2]+bb[ni]) | ((unsigned)f2bf(acc[mi][ni][3]+bb[ni])<<16);
        *(u32x2*)((char*)gxw + (fb + (size_t)lane*4)*2) = v;
      }
    }
    return;
  }

  // ======== LSTM part (32 steps; acc=0 -> MFMA -> gx added in gate phase) ========
  int bid=blockIdx.x, dir=bid>>4, blk=bid&15;
  int tbase = chunk*32;
  int row = lane&15, rgrp = lane>>4;

  const char* whpw = (const char*)whp + (size_t)(dir*8+w)*65536;

  #pragma unroll
  for (int i=0;i<16;i++){
    int kt=i>>1, p=i&1;
    gl_lds16(whpw + (kt*8+5+p)*1024 + lane*16, (char*)wh_lds + (w*16 + i)*1024);
  }
  bf16x8 whr[8][5];
  #pragma unroll
  for (int kt=0;kt<8;kt++)
    #pragma unroll
    for (int nt=0;nt<5;nt++)
      whr[kt][nt] = ld8(whpw + (kt*8+nt)*1024 + lane*16);

  float sst[2][4];
  if (chunk==0){
    #pragma unroll
    for (int p=0;p<2;p++)
      #pragma unroll
      for (int r=0;r<4;r++) sst[p][r]=0.f;
    *(short8*)&qbuf0[tid*8] = (short8){0,0,0,0,0,0,0,0};
  } else {
    f32x4 s0 = *(const f32x4*)&ssave[((size_t)bid*512+tid)*8];
    f32x4 s1 = *(const f32x4*)&ssave[((size_t)bid*512+tid)*8 + 4];
    sst[0][0]=s0[0]; sst[0][1]=s0[1]; sst[0][2]=s0[2]; sst[0][3]=s0[3];
    sst[1][0]=s1[0]; sst[1][1]=s1[1]; sst[1][2]=s1[2]; sst[1][3]=s1[3];
    *(short8*)&qbuf0[tid*8] = *(const short8*)&qsave[(size_t)bid*4096 + tid*8];
  }

  int aoff[8];
  #pragma unroll
  for (int kt=0;kt<8;kt++)
    aoff[kt] = ((row)*512 + ((kt*64 + rgrp*16) ^ ((lane&7)<<4))) >> 1;
  int woff[2][4];
  #pragma unroll
  for (int p=0;p<2;p++)
    #pragma unroll
    for (int r=0;r<4;r++){
      int bb = rgrp*4 + r;
      woff[p][r] = (bb*512 + ((w*64 + p*32 + row*2) ^ ((bb&7)<<4))) >> 1;
    }
  int qoutbase = dir*65536 + blk*4096 + w*32 + row;
  const char* gxb = (const char*)gxr + ((size_t)(dir*16+blk)*8 + w)*4096 + (size_t)lane*8;

  asm volatile("s_waitcnt vmcnt(0)" ::: "memory");
  __syncthreads();

#define STEP(TL, QR, QW) { \
    const int tl = (TL); \
    /* gx loads issue here; consumed only in the gate phase -> latency hides under MFMA */ \
    const char* gp = gxb + (size_t)tl*1048576; \
    u32x2 gt[8]; \
    _Pragma("unroll") for (int nt=0;nt<8;nt++) gt[nt] = *(const u32x2*)(const void*)(gp + nt*512); \
    f32x4 acc[8]; \
    _Pragma("unroll") for (int nt=0;nt<8;nt++) acc[nt] = (f32x4){0.f,0.f,0.f,0.f}; \
    bf16x8 Afr[2], sA[3]; \
    Afr[0] = ld8(&QR[aoff[0]]); \
    sA[0]  = ld8(whpw + (0*8+7)*1024 + lane*16); \
    sA[1]  = ld8(whpw + (1*8+7)*1024 + lane*16); \
    _Pragma("unroll") for (int kt=0;kt<8;kt++){ \
      const int cur = kt&1, nxt = (kt+1)&1; \
      if (kt<7) Afr[nxt] = ld8(&QR[aoff[kt+1]]); \
      if (kt<6) sA[(kt+2)%3] = ld8(whpw + ((kt+2)*8+7)*1024 + lane*16); \
      bf16x8 lA = ld8((char*)wh_lds + (w*16 + kt*2+0)*1024 + lane*16); \
      bf16x8 lB = ld8((char*)wh_lds + (w*16 + kt*2+1)*1024 + lane*16); \
      acc[0] = __builtin_amdgcn_mfma_f32_16x16x32_bf16(Afr[cur], whr[kt][0], acc[0], 0,0,0); \
      acc[1] = __builtin_amdgcn_mfma_f32_16x16x32_bf16(Afr[cur], whr[kt][1], acc[1], 0,0,0); \
      acc[2] = __builtin_amdgcn_mfma_f32_16x16x32_bf16(Afr[cur], whr[kt][2], acc[2], 0,0,0); \
      acc[3] = __builtin_amdgcn_mfma_f32_16x16x32_bf16(Afr[cur], whr[kt][3], acc[3], 0,0,0); \
      acc[4] = __builtin_amdgcn_mfma_f32_16x16x32_bf16(Afr[cur], whr[kt][4], acc[4], 0,0,0); \
      acc[5] = __builtin_amdgcn_mfma_f32_16x16x32_bf16(Afr[cur], lA,         acc[5], 0,0,0); \
      acc[6] = __builtin_amdgcn_mfma_f32_16x16x32_bf16(Afr[cur], lB,         acc[6], 0,0,0); \
      acc[7] = __builtin_amdgcn_mfma_f32_16x16x32_bf16(Afr[cur], sA[kt%3],   acc[7], 0,0,0); \
    } \
    float qv[2][4]; \
    _Pragma("unroll") for (int p=0;p<2;p++) \
      _Pragma("unroll") for (int r=0;r<4;r++){ \
        unsigned uf = (r<2)? (gt[0+p].x >> (r*16)) : (gt[0+p].y >> ((r-2)*16)); \
        unsigned ui = (r<2)? (gt[2+p].x >> (r*16)) : (gt[2+p].y >> ((r-2)*16)); \
        unsigned ua = (r<2)? (gt[4+p].x >> (r*16)) : (gt[4+p].y >> ((r-2)*16)); \
        unsigned uo = (r<2)? (gt[6+p].x >> (r*16)) : (gt[6+p].y >> ((r-2)*16)); \
        float fg = sigf (acc[0+p][r] + bf2f((u16)uf)); \
        float ig = sigf (acc[2+p][r] + bf2f((u16)ui)); \
        float ag = tanh_(acc[4+p][r] + bf2f((u16)ua)); \
        float og = sigf (acc[6+p][r] + bf2f((u16)uo)); \
        float s = fg*sst[p][r] + ig*ag; sst[p][r] = s; \
        qv[p][r] = og*tanh_(s); \
      } \
    if (tbase + tl == 511){ \
      _Pragma("unroll") for (int p=0;p<2;p++) \
        _Pragma("unroll") for (int r=0;r<4;r++) \
          qout[qoutbase + (rgrp*4 + r)*256 + p*16] = qv[p][r]; \
    } else { \
      _Pragma("unroll") for (int p=0;p<2;p++) \
        _Pragma("unroll") for (int r=0;r<4;r++) \
          QW[woff[p][r]] = f2bf(qv[p][r]); \
    } \
    __syncthreads(); \
  }

  for (int t2=0;t2<32;t2+=2){
    STEP(t2,   qbuf0, qbuf1)
    STEP(t2+1, qbuf1, qbuf0)
  }
#undef STEP

  if (chunk < 15){
    *(short8*)&qsave[(size_t)bid*4096 + tid*8] = *(const short8*)&qbuf0[tid*8];
    f32x4 s0 = (f32x4){sst[0][0],sst[0][1],sst[0][2],sst[0][3]};
    f32x4 s1 = (f32x4){sst[1][0],sst[1][1],sst[1][2],sst[1][3]};
    *(f32x4*)&ssave[((size_t)bid*512+tid)*8]     = s0;
    *(f32x4*)&ssave[((size_t)bid*512+tid)*8 + 4] = s1;
  }
}

// ---------------- k3: out = [q_f|q_r] @ w3 + b3 ----------------
__global__ __launch_bounds__(256) void disc_k3(const float* __restrict__ qout,
    const float* __restrict__ w3, const float* __restrict__ b3, float* __restrict__ out)
{
  int b = threadIdx.x;
  const float* qf = qout + (size_t)b*256;
  const float* qr = qout + 65536 + (size_t)b*256;
  float acc = b3[0];
  #pragma unroll 4
  for (int h=0;h<256;h++) acc += qf[h]*w3[h] + qr[h]*w3[256+h];
  out[b] = acc;
}

extern "C" void kernel_launch(void* const* d_in, const int* in_sizes, int n_in,
                              void* d_out, int out_size, void* d_ws, size_t ws_size,
                              hipStream_t stream)
{
  const float* x0   = (const float*)d_in[0];
  const float* embw = (const float*)d_in[1];
  const float* w1   = (const float*)d_in[2];
  const float* b1   = (const float*)d_in[3];
  const float* w2   = (const float*)d_in[4];
  const float* b2   = (const float*)d_in[5];
  const float* wi_f = (const float*)d_in[6];
  const float* bi_f = (const float*)d_in[7];
  const float* wh_f = (const float*)d_in[8];
  const float* bh_f = (const float*)d_in[9];
  const float* wi_r = (const float*)d_in[10];
  const float* bi_r = (const float*)d_in[11];
  const float* wh_r = (const float*)d_in[12];
  const float* bh_r = (const float*)d_in[13];
  const float* w3   = (const float*)d_in[14];
  const float* b3   = (const float*)d_in[15];

  const size_t NEED = 137797632ull;
  if (ws_size < NEED){           // diagnostic sentinel: absmax ~1e9 => ws too small
    disc_wsfail<<<dim3(1), dim3(1), 0, stream>>>((float*)d_out);
    return;
  }

  char* ws = (char*)d_ws;
  u16*   gx0   = (u16*)  (ws);                    // 33,554,432 B (32-step gx chunk A)
  u16*   gx1   = (u16*)  (ws + 33554432ull);      // 33,554,432 B (chunk B)
  u16*   x2    = (u16*)  (ws);                    // overlays gx0+gx1 (used pre-k1c only)
  u16*   x3t   = (u16*)  (ws + 67108864ull);      // 67,108,864 B
  u16*   whp   = (u16*)  (ws + 134217728ull);     // 1,048,576 B
  u16*   w1eT  = (u16*)  (ws + 135266304ull);     // 32,768 B
  u16*   w2bT  = (u16*)  (ws + 135299072ull);     // 131,072 B
  u16*   wibT  = (u16*)  (ws + 135430144ull);     // 1,048,576 B
  float* biasf = (float*)(ws + 136478720ull);     // 8,192 B
  float* qout  = (float*)(ws + 136486912ull);     // 524,288 B
  u16*   qsave = (u16*)  (ws + 137011200ull);     // 262,144 B
  float* ssave = (float*)(ws + 137273344ull);     // 524,288 B  (end 137,797,632)

  disc_prep<<<dim3(4424), dim3(256), 0, stream>>>(embw, w1, w2, wi_f, wi_r, wh_f, wh_r,
                                                  bi_f, bh_f, bi_r, bh_r,
                                                  w1eT, w2bT, wibT, whp, biasf);
  disc_k1a<<<dim3(2048), dim3(256), 0, stream>>>(x0, w1eT, b1, x2);
  disc_k1b<<<dim3(2048), dim3(256), 0, stream>>>(x2, w2bT, b2, x3t);
  disc_k1c<<<dim3(1024), dim3(256), 0, stream>>>(x3t, wibT, biasf, gx0, 0);
  for (int c = 0; c < 16; ++c){
    const u16* gr = (c & 1) ? gx1 : gx0;
    u16*       gw = (c & 1) ? gx0 : gx1;
    int grid = (c < 15) ? 1056 : 32;
    disc_fused<<<dim3(grid), dim3(512), 0, stream>>>(gr, gw, whp, x3t, wibT, biasf,
                                                     qsave, ssave, qout, c);
  }
  disc_k3<<<dim3(1), dim3(256), 0, stream>>>(qout, w3, b3, (float*)d_out);
}

// Round 17
// 1831.698 us; speedup vs baseline: 1.3937x; 1.3937x over previous
//
#include <hip/hip_runtime.h>

// Discriminator: emb+MLP (GEMMs) -> bidirectional LSTM (wh-resident persistent blocks) -> proj
// B=256 T=512 HD=256 FEAT=48 G=1024
// R15 = R13 exact revert (best: 1834us). LSTM step: whr[8][5] AGPR / nt5-6 LDS / nt7
// 1-deep stream; bf16 gx loaded+converted at step head; qbuf double-buffer (1 barrier/step).
// k1c(c+1) fused into k2(c)'s launch as blocks 32..1055. The step's register allocation is
// exactly at the 2-wave/SIMD unified-file wall: R7/R8/R10/R12/R14 all regressed by adding
// liveness. Do not perturb the step without freeing registers elsewhere first.

#define DI __device__ __forceinline__
typedef unsigned short u16;
typedef __attribute__((ext_vector_type(8))) __bf16 bf16x8;
typedef __attribute__((ext_vector_type(8))) short short8;
typedef __attribute__((ext_vector_type(4))) float f32x4;
typedef __attribute__((ext_vector_type(2))) unsigned int u32x2;

DI float bf2f(u16 u){ unsigned v = ((unsigned)u)<<16; float f; __builtin_memcpy(&f,&v,4); return f; }
DI u16 f2bf(float f){ unsigned u; __builtin_memcpy(&u,&f,4);
  unsigned r = (u + 0x7fffu + ((u>>16)&1u))>>16; return (u16)r; }
DI float sigf(float x){ return __builtin_amdgcn_rcpf(1.f + __builtin_amdgcn_exp2f(-1.44269504f*x)); }
DI float tanh_(float x){ return 1.f - 2.f*__builtin_amdgcn_rcpf(1.f + __builtin_amdgcn_exp2f(2.88539008f*x)); }

// async global->LDS, 16B/lane; LDS dest = wave-uniform base + lane*16 (HW rule).
DI void gl_lds16(const void* g, void* lds){
  __builtin_amdgcn_global_load_lds(
    (const __attribute__((address_space(1))) unsigned int*)g,
    (__attribute__((address_space(3))) unsigned int*)lds,
    16, 0, 0);
}
DI bf16x8 ld8(const void* p){ return *(const bf16x8*)p; }

__global__ void disc_wsfail(float* out){ out[0] = 1.0e9f; }

// ---------------- prep: weight transforms (R2 layouts) ----------------
__global__ __launch_bounds__(256) void disc_prep(
    const float* __restrict__ embw, const float* __restrict__ w1, const float* __restrict__ w2,
    const float* __restrict__ wi_f, const float* __restrict__ wi_r,
    const float* __restrict__ wh_f, const float* __restrict__ wh_r,
    const float* __restrict__ bi_f, const float* __restrict__ bh_f,
    const float* __restrict__ bi_r, const float* __restrict__ bh_r,
    u16* __restrict__ w1effT, u16* __restrict__ w2bT, u16* __restrict__ wibT,
    u16* __restrict__ whp, float* __restrict__ biasf)
{
  int bx = blockIdx.x, tid = threadIdx.x;
  if (bx < 64) {                           // w1effT[n][f] 256x64, emb folded, f>=48 zero
    int i = bx*256 + tid; int n = i>>6, f = i&63;
    float v = 0.f;
    if (f < 8) v = w1[f*256 + n];
    else if (f < 48) {
      int ff = f-8, c = ff/10, cls = ff%10;
      #pragma unroll
      for (int e=0;e<8;e++) v += embw[(c*10+cls)*8 + e] * w1[(8 + c*8 + e)*256 + n];
    }
    w1effT[n*64 + f] = f2bf(v);
  } else if (bx < 320) {                   // w2bT[n][k] 256x256
    int i = (bx-64)*256 + tid; int n = i>>8, k = i&255;
    w2bT[i] = f2bf(w2[k*256 + n]);
  } else if (bx < 2368) {                  // wibT[n][k] 2048x256, n = dir*1024+g
    int i = (bx-320)*256 + tid; int n = i>>8, k = i&255;
    const float* wi = (n < 1024) ? wi_f : wi_r; int g = n & 1023;
    wibT[i] = f2bf(wi[k*1024 + g]);
  } else if (bx < 4416) {                  // whp[dir][w][kt][nt][lane][j] B-frag order
    int i = (bx-2368)*256 + tid;
    int j = i&7, lane = (i>>3)&63, nt = (i>>9)&7, kt = (i>>12)&7, w = (i>>15)&7, dir = (i>>18)&1;
    int k = kt*32 + (lane>>4)*8 + j;
    int g = (nt>>1)*256 + w*32 + (nt&1)*16 + (lane&15);
    const float* wh = dir ? wh_r : wh_f;
    whp[i] = f2bf(wh[k*1024 + g]);
  } else {                                 // biasf[dir*1024+g] = bi+bh
    int i = (bx-4416)*256 + tid;
    if (i < 2048) { int dir = i>>10, g = i&1023;
      biasf[i] = dir ? (bi_r[g]+bh_r[g]) : (bi_f[g]+bh_f[g]); }
  }
}

// ---------------- k1a: x2 = lrelu(x0 @ w1eff + b1), bf16 [b*512+t][256] ----------------
__global__ __launch_bounds__(256) void disc_k1a(const float* __restrict__ x0,
    const u16* __restrict__ w1effT, const float* __restrict__ b1, u16* __restrict__ x2)
{
  __shared__ __align__(16) u16 a_lds[64*64];
  __shared__ __align__(16) u16 b_lds[256*64];
  int tid=threadIdx.x, lane=tid&63, wv=tid>>6;
  int m0 = blockIdx.x*64;
  #pragma unroll
  for (int r2=0;r2<8;r2++){
    int c = r2*256 + tid;
    gl_lds16((const char*)w1effT + (size_t)c*16, (char*)b_lds + (r2*256 + wv*64)*16);
  }
  if (tid < 128){
    int row = tid>>1, half = tid&1;
    const float* src = x0 + (size_t)(m0+row)*48 + half*24;
    u16 tmp[24];
    #pragma unroll
    for (int i=0;i<24;i++) tmp[i] = f2bf(src[i]);
    #pragma unroll
    for (int i=0;i<3;i++) *(short8*)&a_lds[row*64 + half*24 + i*8] = *(short8*)&tmp[i*8];
    if (half){ short8 z = (short8){0,0,0,0,0,0,0,0};
      *(short8*)&a_lds[row*64 + 48] = z; *(short8*)&a_lds[row*64 + 56] = z; }
  }
  asm volatile("s_waitcnt vmcnt(0)" ::: "memory");
  __syncthreads();
  bf16x8 Af0 = ld8(&a_lds[(wv*16 + (lane&15))*64 + (lane>>4)*8]);
  bf16x8 Af1 = ld8(&a_lds[(wv*16 + (lane&15))*64 + 32 + (lane>>4)*8]);
  f32x4 acc[16];
  #pragma unroll
  for (int ni=0;ni<16;ni++){
    acc[ni] = (f32x4){0.f,0.f,0.f,0.f};
    bf16x8 B0 = ld8(&b_lds[(ni*16 + (lane&15))*64 + (lane>>4)*8]);
    bf16x8 B1 = ld8(&b_lds[(ni*16 + (lane&15))*64 + 32 + (lane>>4)*8]);
    acc[ni] = __builtin_amdgcn_mfma_f32_16x16x32_bf16(Af0, B0, acc[ni], 0,0,0);
    acc[ni] = __builtin_amdgcn_mfma_f32_16x16x32_bf16(Af1, B1, acc[ni], 0,0,0);
  }
  #pragma unroll
  for (int ni=0;ni<16;ni++){
    float bb = b1[ni*16 + (lane&15)];
    #pragma unroll
    for (int r=0;r<4;r++){
      float v = acc[ni][r] + bb; v = v>=0.f ? v : 0.1f*v;
      int row = m0 + wv*16 + (lane>>4)*4 + r;
      x2[(size_t)row*256 + ni*16 + (lane&15)] = f2bf(v);
    }
  }
}

// ---------------- k1b: x3t = lrelu(x2 @ w2 + b2), permuted [t][b][256] ----------------
__global__ __launch_bounds__(256) void disc_k1b(const u16* __restrict__ x2,
    const u16* __restrict__ w2bT, const float* __restrict__ b2, u16* __restrict__ x3t)
{
  __shared__ __align__(16) u16 a_lds[64*64];
  __shared__ __align__(16) u16 b_lds[256*64];
  int tid=threadIdx.x, lane=tid&63, wv=tid>>6;
  int m0 = blockIdx.x*64;
  f32x4 acc[16];
  #pragma unroll
  for (int ni=0;ni<16;ni++) acc[ni] = (f32x4){0.f,0.f,0.f,0.f};
  for (int kt=0;kt<4;kt++){
    #pragma unroll
    for (int r2=0;r2<2;r2++){
      int c = r2*256 + tid, row = c>>3, cb = (c&7)*16;
      gl_lds16((const char*)x2 + (size_t)(m0+row)*512 + kt*128 + cb,
               (char*)a_lds + (r2*256 + wv*64)*16);
    }
    #pragma unroll
    for (int r2=0;r2<8;r2++){
      int c = r2*256 + tid, row = c>>3, cb = (c&7)*16;
      gl_lds16((const char*)w2bT + (size_t)row*512 + kt*128 + cb,
               (char*)b_lds + (r2*256 + wv*64)*16);
    }
    asm volatile("s_waitcnt vmcnt(0)" ::: "memory");
    __syncthreads();
    bf16x8 Af0 = ld8(&a_lds[(wv*16 + (lane&15))*64 + (lane>>4)*8]);
    bf16x8 Af1 = ld8(&a_lds[(wv*16 + (lane&15))*64 + 32 + (lane>>4)*8]);
    #pragma unroll
    for (int ni=0;ni<16;ni++){
      bf16x8 B0 = ld8(&b_lds[(ni*16 + (lane&15))*64 + (lane>>4)*8]);
      bf16x8 B1 = ld8(&b_lds[(ni*16 + (lane&15))*64 + 32 + (lane>>4)*8]);
      acc[ni] = __builtin_amdgcn_mfma_f32_16x16x32_bf16(Af0, B0, acc[ni], 0,0,0);
      acc[ni] = __builtin_amdgcn_mfma_f32_16x16x32_bf16(Af1, B1, acc[ni], 0,0,0);
    }
    __syncthreads();
  }
  #pragma unroll
  for (int ni=0;ni<16;ni++){
    float bb = b2[ni*16 + (lane&15)];
    #pragma unroll
    for (int r=0;r<4;r++){
      float v = acc[ni][r] + bb; v = v>=0.f ? v : 0.1f*v;
      int rowg = m0 + wv*16 + (lane>>4)*4 + r;     // = b*512 + t
      int b = rowg>>9, t = rowg&511;
      x3t[((size_t)t*256 + b)*256 + ni*16 + (lane&15)] = f2bf(v);
    }
  }
}

// ---------------- k1c (standalone, 32-step chunk): gxc = bf16(x3 @ wi + bias) ----------
// gxc u16 idx = ((((tloc*2+dir)*16+blk)*8+w)*8+nt)*256 + lane*4 + r, tloc in [0,32)
__global__ __launch_bounds__(256) void disc_k1c(const u16* __restrict__ x3t,
    const u16* __restrict__ wibT, const float* __restrict__ biasf,
    u16* __restrict__ gxc, int chunk)
{
  __shared__ __align__(16) u16 a_lds[128*64];
  __shared__ __align__(16) u16 b_lds[128*64];
  int tid=threadIdx.x, lane=tid&63, wv=tid>>6;
  int id = (blockIdx.x & 7)*128 + (blockIdx.x >> 3);   // XCD swizzle, 1024 blocks
  int dirn = id >> 9;
  int rem  = id & 511;
  int tloc = rem >> 4;           // 0..31
  int msub = (rem >> 3) & 1;
  int nt8  = rem & 7;
  int tp    = chunk*32 + tloc;
  int tglob = dirn ? (511 - tp) : tp;
  int m0 = tglob*256 + msub*128;
  int n0 = dirn*1024 + nt8*128;
  int wm = wv>>1, wn = wv&1;
  f32x4 acc[4][4];
  #pragma unroll
  for (int mi=0;mi<4;mi++)
    #pragma unroll
    for (int ni=0;ni<4;ni++) acc[mi][ni] = (f32x4){0.f,0.f,0.f,0.f};
  for (int kt=0;kt<4;kt++){
    #pragma unroll
    for (int r2=0;r2<4;r2++){
      int c = r2*256 + tid, row = c>>3, cb = (c&7)*16;
      gl_lds16((const char*)x3t + (size_t)(m0+row)*512 + kt*128 + cb,
               (char*)a_lds + (r2*256 + wv*64)*16);
    }
    #pragma unroll
    for (int r2=0;r2<4;r2++){
      int c = r2*256 + tid, row = c>>3, cb = (c&7)*16;
      gl_lds16((const char*)wibT + (size_t)(n0+row)*512 + kt*128 + cb,
               (char*)b_lds + (r2*256 + wv*64)*16);
    }
    asm volatile("s_waitcnt vmcnt(0)" ::: "memory");
    __syncthreads();
    bf16x8 Af[4][2], Bf[4][2];
    #pragma unroll
    for (int mi=0;mi<4;mi++){
      Af[mi][0] = ld8(&a_lds[(wm*64+mi*16+(lane&15))*64 + (lane>>4)*8]);
      Af[mi][1] = ld8(&a_lds[(wm*64+mi*16+(lane&15))*64 + 32 + (lane>>4)*8]);
    }
    #pragma unroll
    for (int ni=0;ni<4;ni++){
      Bf[ni][0] = ld8(&b_lds[(wn*64+ni*16+(lane&15))*64 + (lane>>4)*8]);
      Bf[ni][1] = ld8(&b_lds[(wn*64+ni*16+(lane&15))*64 + 32 + (lane>>4)*8]);
    }
    #pragma unroll
    for (int ks=0;ks<2;ks++)
      #pragma unroll
      for (int mi=0;mi<4;mi++)
        #pragma unroll
        for (int ni=0;ni<4;ni++)
          acc[mi][ni] = __builtin_amdgcn_mfma_f32_16x16x32_bf16(Af[mi][ks], Bf[ni][ks], acc[mi][ni], 0,0,0);
    __syncthreads();
  }
  float bb[4];
  #pragma unroll
  for (int ni=0;ni<4;ni++) bb[ni] = biasf[n0 + wn*64 + ni*16 + (lane&15)];
  #pragma unroll
  for (int mi=0;mi<4;mi++){
    int bbase = msub*128 + wm*64 + mi*16;
    #pragma unroll
    for (int ni=0;ni<4;ni++){
      int g0 = (n0 + wn*64 + ni*16) & 1023;
      int gt = g0>>8, h0 = g0&255;
      int w8 = h0>>5, p = (h0>>4)&1, nt = gt*2 + p;
      size_t fb = (((((size_t)tloc*2 + dirn)*16 + (bbase>>4))*8 + w8)*8 + nt)*256;
      u32x2 v;
      v.x = (unsigned)f2bf(acc[mi][ni][0]+bb[ni]) | ((unsigned)f2bf(acc[mi][ni][1]+bb[ni])<<16);
      v.y = (unsigned)f2bf(acc[mi][ni][2]+bb[ni]) | ((unsigned)f2bf(acc[mi][ni][3]+bb[ni])<<16);
      *(u32x2*)((char*)gxc + (fb + (size_t)lane*4)*2) = v;
    }
  }
}

// ---------------- fused: blocks 0-31 = LSTM chunk c (reads gxr); blocks 32-1055 = ------
// GEMM chunk c+1 into gxw (8 waves, 4x2 frags/wave). 512 thr, uniform barriers.
__global__ __launch_bounds__(512) __attribute__((amdgpu_waves_per_eu(2, 2)))
void disc_fused(const u16* __restrict__ gxr, u16* __restrict__ gxw,
                const u16* __restrict__ whp,
                const u16* __restrict__ x3t, const u16* __restrict__ wibT,
                const float* __restrict__ biasf,
                u16* __restrict__ qsave, float* __restrict__ ssave,
                float* __restrict__ qout, int chunk)
{
  __shared__ __align__(16) u16 wh_lds[65536];   // LSTM: 128KB wh; GEMM: a_lds/b_lds reuse
  __shared__ __align__(16) u16 qbuf0[4096];
  __shared__ __align__(16) u16 qbuf1[4096];
  int tid=threadIdx.x, lane=tid&63, w=tid>>6;

  if (blockIdx.x >= 32){
    // ======== GEMM part: gx chunk+1 -> gxw ========
    u16* a_lds = wh_lds;          // 16 KB
    u16* b_lds = wh_lds + 8192;   // 16 KB
    int gid = (int)blockIdx.x - 32;
    int id = (gid & 7)*128 + (gid >> 3);   // XCD swizzle, 1024 blocks
    int dirn = id >> 9;
    int rem  = id & 511;
    int tloc = rem >> 4;          // 0..31
    int msub = (rem >> 3) & 1;
    int nt8  = rem & 7;
    int tp    = (chunk+1)*32 + tloc;
    int tglob = dirn ? (511 - tp) : tp;
    int m0 = tglob*256 + msub*128;
    int n0 = dirn*1024 + nt8*128;
    int wm = w>>2, wn = w&3;      // 2 x 4 wave grid; wave = 64 rows x 32 cols
    f32x4 acc[4][2];
    #pragma unroll
    for (int mi=0;mi<4;mi++)
      #pragma unroll
      for (int ni=0;ni<2;ni++) acc[mi][ni] = (f32x4){0.f,0.f,0.f,0.f};
    for (int kt=0;kt<4;kt++){
      #pragma unroll
      for (int r2=0;r2<2;r2++){
        int c = r2*512 + tid, row = c>>3, cb = (c&7)*16;
        gl_lds16((const char*)x3t + (size_t)(m0+row)*512 + kt*128 + cb,
                 (char*)a_lds + (r2*512 + w*64)*16);
        int c2 = r2*512 + tid, row2 = c2>>3, cb2 = (c2&7)*16;
        gl_lds16((const char*)wibT + (size_t)(n0+row2)*512 + kt*128 + cb2,
                 (char*)b_lds + (r2*512 + w*64)*16);
      }
      asm volatile("s_waitcnt vmcnt(0)" ::: "memory");
      __syncthreads();
      bf16x8 Af[4][2], Bf[2][2];
      #pragma unroll
      for (int mi=0;mi<4;mi++){
        Af[mi][0] = ld8(&a_lds[(wm*64+mi*16+(lane&15))*64 + (lane>>4)*8]);
        Af[mi][1] = ld8(&a_lds[(wm*64+mi*16+(lane&15))*64 + 32 + (lane>>4)*8]);
      }
      #pragma unroll
      for (int ni=0;ni<2;ni++){
        Bf[ni][0] = ld8(&b_lds[(wn*32+ni*16+(lane&15))*64 + (lane>>4)*8]);
        Bf[ni][1] = ld8(&b_lds[(wn*32+ni*16+(lane&15))*64 + 32 + (lane>>4)*8]);
      }
      #pragma unroll
      for (int ks=0;ks<2;ks++)
        #pragma unroll
        for (int mi=0;mi<4;mi++)
          #pragma unroll
          for (int ni=0;ni<2;ni++)
            acc[mi][ni] = __builtin_amdgcn_mfma_f32_16x16x32_bf16(Af[mi][ks], Bf[ni][ks], acc[mi][ni], 0,0,0);
      __syncthreads();
    }
    float bb[2];
    #pragma unroll
    for (int ni=0;ni<2;ni++) bb[ni] = biasf[n0 + wn*32 + ni*16 + (lane&15)];
    #pragma unroll
    for (int mi=0;mi<4;mi++){
      int bbase = msub*128 + wm*64 + mi*16;
      #pragma unroll
      for (int ni=0;ni<2;ni++){
        int g0 = (n0 + wn*32 + ni*16) & 1023;
        int gt = g0>>8, h0 = g0&255;
        int w8 = h0>>5, p = (h0>>4)&1, nt = gt*2 + p;
        size_t fb = (((((size_t)tloc*2 + dirn)*16 + (bbase>>4))*8 + w8)*8 + nt)*256;
        u32x2 v;
        v.x = (unsigned)f2bf(acc[mi][ni][0]+bb[ni]) | ((unsigned)f2bf(acc[mi][ni][1]+bb[ni])<<16);
        v.y = (unsigned)f2bf(acc[mi][ni][2]+bb[ni]) | ((unsigned)f2bf(acc[mi][ni][3]+bb[ni])<<16);
        *(u32x2*)((char*)gxw + (fb + (size_t)lane*4)*2) = v;
      }
    }
    return;
  }

  // ======== LSTM part (R11 k2 verbatim, 32 steps) ========
  int bid=blockIdx.x, dir=bid>>4, blk=bid&15;
  int tbase = chunk*32;
  int row = lane&15, rgrp = lane>>4;

  const char* whpw = (const char*)whp + (size_t)(dir*8+w)*65536;

  #pragma unroll
  for (int i=0;i<16;i++){
    int kt=i>>1, p=i&1;
    gl_lds16(whpw + (kt*8+5+p)*1024 + lane*16, (char*)wh_lds + (w*16 + i)*1024);
  }
  bf16x8 whr[8][5];
  #pragma unroll
  for (int kt=0;kt<8;kt++)
    #pragma unroll
    for (int nt=0;nt<5;nt++)
      whr[kt][nt] = ld8(whpw + (kt*8+nt)*1024 + lane*16);

  float sst[2][4];
  if (chunk==0){
    #pragma unroll
    for (int p=0;p<2;p++)
      #pragma unroll
      for (int r=0;r<4;r++) sst[p][r]=0.f;
    *(short8*)&qbuf0[tid*8] = (short8){0,0,0,0,0,0,0,0};
  } else {
    f32x4 s0 = *(const f32x4*)&ssave[((size_t)bid*512+tid)*8];
    f32x4 s1 = *(const f32x4*)&ssave[((size_t)bid*512+tid)*8 + 4];
    sst[0][0]=s0[0]; sst[0][1]=s0[1]; sst[0][2]=s0[2]; sst[0][3]=s0[3];
    sst[1][0]=s1[0]; sst[1][1]=s1[1]; sst[1][2]=s1[2]; sst[1][3]=s1[3];
    *(short8*)&qbuf0[tid*8] = *(const short8*)&qsave[(size_t)bid*4096 + tid*8];
  }

  int aoff[8];
  #pragma unroll
  for (int kt=0;kt<8;kt++)
    aoff[kt] = ((row)*512 + ((kt*64 + rgrp*16) ^ ((lane&7)<<4))) >> 1;
  int woff[2][4];
  #pragma unroll
  for (int p=0;p<2;p++)
    #pragma unroll
    for (int r=0;r<4;r++){
      int bb = rgrp*4 + r;
      woff[p][r] = (bb*512 + ((w*64 + p*32 + row*2) ^ ((bb&7)<<4))) >> 1;
    }
  int qoutbase = dir*65536 + blk*4096 + w*32 + row;
  const char* gxb = (const char*)gxr + ((size_t)(dir*16+blk)*8 + w)*4096 + (size_t)lane*8;

  asm volatile("s_waitcnt vmcnt(0)" ::: "memory");
  __syncthreads();

#define STEP(TL, QR, QW) { \
    const int tl = (TL); \
    const char* gp = gxb + (size_t)tl*1048576; \
    u32x2 gt[8]; \
    _Pragma("unroll") for (int nt=0;nt<8;nt++) gt[nt] = *(const u32x2*)(const void*)(gp + nt*512); \
    f32x4 acc[8]; \
    _Pragma("unroll") for (int nt=0;nt<8;nt++){ \
      acc[nt][0] = bf2f((u16)(gt[nt].x));       acc[nt][1] = bf2f((u16)(gt[nt].x >> 16)); \
      acc[nt][2] = bf2f((u16)(gt[nt].y));       acc[nt][3] = bf2f((u16)(gt[nt].y >> 16)); \
    } \
    bf16x8 Afr[2], sA[2]; \
    Afr[0] = ld8(&QR[aoff[0]]); \
    sA[0]  = ld8(whpw + (0*8+7)*1024 + lane*16); \
    _Pragma("unroll") for (int kt=0;kt<8;kt++){ \
      const int cur = kt&1, nxt = (kt+1)&1; \
      if (kt<7){ \
        Afr[nxt] = ld8(&QR[aoff[kt+1]]); \
        sA[nxt]  = ld8(whpw + ((kt+1)*8+7)*1024 + lane*16); \
      } \
      bf16x8 lA = ld8((char*)wh_lds + (w*16 + kt*2+0)*1024 + lane*16); \
      bf16x8 lB = ld8((char*)wh_lds + (w*16 + kt*2+1)*1024 + lane*16); \
      acc[0] = __builtin_amdgcn_mfma_f32_16x16x32_bf16(Afr[cur], whr[kt][0], acc[0], 0,0,0); \
      acc[1] = __builtin_amdgcn_mfma_f32_16x16x32_bf16(Afr[cur], whr[kt][1], acc[1], 0,0,0); \
      acc[2] = __builtin_amdgcn_mfma_f32_16x16x32_bf16(Afr[cur], whr[kt][2], acc[2], 0,0,0); \
      acc[3] = __builtin_amdgcn_mfma_f32_16x16x32_bf16(Afr[cur], whr[kt][3], acc[3], 0,0,0); \
      acc[4] = __builtin_amdgcn_mfma_f32_16x16x32_bf16(Afr[cur], whr[kt][4], acc[4], 0,0,0); \
      acc[5] = __builtin_amdgcn_mfma_f32_16x16x32_bf16(Afr[cur], lA,         acc[5], 0,0,0); \
      acc[6] = __builtin_amdgcn_mfma_f32_16x16x32_bf16(Afr[cur], lB,         acc[6], 0,0,0); \
      acc[7] = __builtin_amdgcn_mfma_f32_16x16x32_bf16(Afr[cur], sA[cur],    acc[7], 0,0,0); \
    } \
    float qv[2][4]; \
    _Pragma("unroll") for (int p=0;p<2;p++) \
      _Pragma("unroll") for (int r=0;r<4;r++){ \
        float fg = sigf (acc[0+p][r]); \
        float ig = sigf (acc[2+p][r]); \
        float ag = tanh_(acc[4+p][r]); \
        float og = sigf (acc[6+p][r]); \
        float s = fg*sst[p][r] + ig*ag; sst[p][r] = s; \
        qv[p][r] = og*tanh_(s); \
      } \
    if (tbase + tl == 511){ \
      _Pragma("unroll") for (int p=0;p<2;p++) \
        _Pragma("unroll") for (int r=0;r<4;r++) \
          qout[qoutbase + (rgrp*4 + r)*256 + p*16] = qv[p][r]; \
    } else { \
      _Pragma("unroll") for (int p=0;p<2;p++) \
        _Pragma("unroll") for (int r=0;r<4;r++) \
          QW[woff[p][r]] = f2bf(qv[p][r]); \
    } \
    __syncthreads(); \
  }

  for (int t2=0;t2<32;t2+=2){
    STEP(t2,   qbuf0, qbuf1)
    STEP(t2+1, qbuf1, qbuf0)
  }
#undef STEP

  if (chunk < 15){
    *(short8*)&qsave[(size_t)bid*4096 + tid*8] = *(const short8*)&qbuf0[tid*8];
    f32x4 s0 = (f32x4){sst[0][0],sst[0][1],sst[0][2],sst[0][3]};
    f32x4 s1 = (f32x4){sst[1][0],sst[1][1],sst[1][2],sst[1][3]};
    *(f32x4*)&ssave[((size_t)bid*512+tid)*8]     = s0;
    *(f32x4*)&ssave[((size_t)bid*512+tid)*8 + 4] = s1;
  }
}

// ---------------- k3: out = [q_f|q_r] @ w3 + b3 ----------------
__global__ __launch_bounds__(256) void disc_k3(const float* __restrict__ qout,
    const float* __restrict__ w3, const float* __restrict__ b3, float* __restrict__ out)
{
  int b = threadIdx.x;
  const float* qf = qout + (size_t)b*256;
  const float* qr = qout + 65536 + (size_t)b*256;
  float acc = b3[0];
  #pragma unroll 4
  for (int h=0;h<256;h++) acc += qf[h]*w3[h] + qr[h]*w3[256+h];
  out[b] = acc;
}

extern "C" void kernel_launch(void* const* d_in, const int* in_sizes, int n_in,
                              void* d_out, int out_size, void* d_ws, size_t ws_size,
                              hipStream_t stream)
{
  const float* x0   = (const float*)d_in[0];
  const float* embw = (const float*)d_in[1];
  const float* w1   = (const float*)d_in[2];
  const float* b1   = (const float*)d_in[3];
  const float* w2   = (const float*)d_in[4];
  const float* b2   = (const float*)d_in[5];
  const float* wi_f = (const float*)d_in[6];
  const float* bi_f = (const float*)d_in[7];
  const float* wh_f = (const float*)d_in[8];
  const float* bh_f = (const float*)d_in[9];
  const float* wi_r = (const float*)d_in[10];
  const float* bi_r = (const float*)d_in[11];
  const float* wh_r = (const float*)d_in[12];
  const float* bh_r = (const float*)d_in[13];
  const float* w3   = (const float*)d_in[14];
  const float* b3   = (const float*)d_in[15];

  const size_t NEED = 137797632ull;
  if (ws_size < NEED){           // diagnostic sentinel: absmax ~1e9 => ws too small
    disc_wsfail<<<dim3(1), dim3(1), 0, stream>>>((float*)d_out);
    return;
  }

  char* ws = (char*)d_ws;
  u16*   gx0   = (u16*)  (ws);                    // 33,554,432 B (32-step gx chunk A)
  u16*   gx1   = (u16*)  (ws + 33554432ull);      // 33,554,432 B (chunk B)
  u16*   x2    = (u16*)  (ws);                    // overlays gx0+gx1 (used pre-k1c only)
  u16*   x3t   = (u16*)  (ws + 67108864ull);      // 67,108,864 B
  u16*   whp   = (u16*)  (ws + 134217728ull);     // 1,048,576 B
  u16*   w1eT  = (u16*)  (ws + 135266304ull);     // 32,768 B
  u16*   w2bT  = (u16*)  (ws + 135299072ull);     // 131,072 B
  u16*   wibT  = (u16*)  (ws + 135430144ull);     // 1,048,576 B
  float* biasf = (float*)(ws + 136478720ull);     // 8,192 B
  float* qout  = (float*)(ws + 136486912ull);     // 524,288 B
  u16*   qsave = (u16*)  (ws + 137011200ull);     // 262,144 B
  float* ssave = (float*)(ws + 137273344ull);     // 524,288 B  (end 137,797,632)

  disc_prep<<<dim3(4424), dim3(256), 0, stream>>>(embw, w1, w2, wi_f, wi_r, wh_f, wh_r,
                                                  bi_f, bh_f, bi_r, bh_r,
                                                  w1eT, w2bT, wibT, whp, biasf);
  disc_k1a<<<dim3(2048), dim3(256), 0, stream>>>(x0, w1eT, b1, x2);
  disc_k1b<<<dim3(2048), dim3(256), 0, stream>>>(x2, w2bT, b2, x3t);
  disc_k1c<<<dim3(1024), dim3(256), 0, stream>>>(x3t, wibT, biasf, gx0, 0);
  for (int c = 0; c < 16; ++c){
    const u16* gr = (c & 1) ? gx1 : gx0;
    u16*       gw = (c & 1) ? gx0 : gx1;
    int grid = (c < 15) ? 1056 : 32;
    disc_fused<<<dim3(grid), dim3(512), 0, stream>>>(gr, gw, whp, x3t, wibT, biasf,
                                                     qsave, ssave, qout, c);
  }
  disc_k3<<<dim3(1), dim3(256), 0, stream>>>(qout, w3, b3, (float*)d_out);
}